// Round 1
// baseline (652.646 us; speedup 1.0000x reference)
//
#include <hip/hip_runtime.h>
#include <hip/hip_bf16.h>

// Problem constants
#define BB 4
#define SS 1024
#define DD 1024
#define HH 16
#define DKH 64
#define EPS_LN 1e-6f

#define M_ROWS 4096   // B*S
#define KK 2048       // concatenated complex K (re|im)

typedef float  floatx4 __attribute__((ext_vector_type(4)));
typedef short  shortx8 __attribute__((ext_vector_type(8)));
#define MFMA16(a, b, c) __builtin_amdgcn_mfma_f32_16x16x32_bf16(a, b, c, 0, 0, 0)

// pack two floats into one u32 of 2 bf16 (low = first) via single HW op (RNE)
__device__ __forceinline__ unsigned pk2(float lo, float hi) {
    unsigned u;
    asm("v_cvt_pk_bf16_f32 %0, %1, %2" : "=v"(u) : "v"(lo), "v"(hi));
    return u;
}

// float -> bf16 (RNE) via the same HW op
__device__ __forceinline__ ushort f2b(float x) {
    return (ushort)(pk2(x, x) & 0xffffu);
}

// negate a bf16x8 fragment (flip sign bits)
__device__ __forceinline__ shortx8 negf(shortx8 x) {
    shortx8 r;
    #pragma unroll
    for (int i = 0; i < 8; ++i) r[i] = (short)(x[i] ^ (short)0x8000);
    return r;
}

// async global->LDS, 16 bytes per lane (lane-contiguous LDS layout required)
__device__ __forceinline__ void gl16(const void* g, void* l) {
    __builtin_amdgcn_global_load_lds(
        (const __attribute__((address_space(1))) unsigned int*)g,
        (__attribute__((address_space(3))) unsigned int*)l, 16, 0, 0);
}

// ---------------------------------------------------------------------------
// pack_x: [4096][1024] fp32 pair -> [4096][2048] bf16  (row = [re | im])
// ---------------------------------------------------------------------------
__global__ __launch_bounds__(256) void pack_x(
    const float* __restrict__ qr, const float* __restrict__ qi,
    const float* __restrict__ kr, const float* __restrict__ ki,
    const float* __restrict__ vr, const float* __restrict__ vi,
    ushort* __restrict__ Xq, ushort* __restrict__ Xk, ushort* __restrict__ Xv)
{
    const int t = blockIdx.y;
    const float* pr = t == 0 ? qr : t == 1 ? kr : vr;
    const float* pi = t == 0 ? qi : t == 1 ? ki : vi;
    ushort* X = t == 0 ? Xq : t == 1 ? Xk : Xv;
    const int idx = blockIdx.x * 256 + threadIdx.x;
    const int row = idx >> 8, c4 = (idx & 255) * 4;
    float4 a = *(const float4*)(pr + (size_t)row * 1024 + c4);
    float4 b = *(const float4*)(pi + (size_t)row * 1024 + c4);
    ushort4 ua; ua.x = f2b(a.x); ua.y = f2b(a.y); ua.z = f2b(a.z); ua.w = f2b(a.w);
    ushort4 ub; ub.x = f2b(b.x); ub.y = f2b(b.y); ub.z = f2b(b.z); ub.w = f2b(b.w);
    *(ushort4*)(X + (size_t)row * KK + c4)        = ua;
    *(ushort4*)(X + (size_t)row * KK + 1024 + c4) = ub;
}

// ---------------------------------------------------------------------------
// pack_w: [1024][1024] fp32 pair -> [2048][2048] bf16
//   row n       = [ wr[n] | -wi[n] ]   (produces Yr)
//   row 1024+n  = [ wi[n] |  wr[n] ]   (produces Yi)
// ---------------------------------------------------------------------------
__global__ __launch_bounds__(256) void pack_w(
    const float* __restrict__ ar, const float* __restrict__ ai,
    const float* __restrict__ br, const float* __restrict__ bi,
    const float* __restrict__ cr, const float* __restrict__ ci,
    const float* __restrict__ dr, const float* __restrict__ di,
    ushort* __restrict__ Bq, ushort* __restrict__ Bk,
    ushort* __restrict__ Bv, ushort* __restrict__ Bf)
{
    const int t = blockIdx.y;
    const float* wr = t == 0 ? ar : t == 1 ? br : t == 2 ? cr : dr;
    const float* wi = t == 0 ? ai : t == 1 ? bi : t == 2 ? ci : di;
    ushort* Bo = t == 0 ? Bq : t == 1 ? Bk : t == 2 ? Bv : Bf;
    const int idx = blockIdx.x * 256 + threadIdx.x;
    const int n = idx >> 8, c4 = (idx & 255) * 4;
    float4 a = *(const float4*)(wr + (size_t)n * 1024 + c4);
    float4 b = *(const float4*)(wi + (size_t)n * 1024 + c4);
    ushort4 ua; ua.x = f2b(a.x);  ua.y = f2b(a.y);  ua.z = f2b(a.z);  ua.w = f2b(a.w);
    ushort4 ub; ub.x = f2b(b.x);  ub.y = f2b(b.y);  ub.z = f2b(b.z);  ub.w = f2b(b.w);
    ushort4 un; un.x = f2b(-b.x); un.y = f2b(-b.y); un.z = f2b(-b.z); un.w = f2b(-b.w);
    *(ushort4*)(Bo + (size_t)n * KK + c4)                 = ua;
    *(ushort4*)(Bo + (size_t)n * KK + 1024 + c4)          = un;
    *(ushort4*)(Bo + (size_t)(1024 + n) * KK + c4)        = ub;
    *(ushort4*)(Bo + (size_t)(1024 + n) * KK + 1024 + c4) = ua;
}

// ---------------------------------------------------------------------------
// bf16 MFMA GEMM body (m97 recipe): C[M, N=2048] = A[M,2048] . B[N,2048]^T
// Epilogue modes:
//   0: QK pack  [m][h][re64|im64] bf16  (scale applied)
//   1: V packs, interleaved complex streams per dv row:
//        Vneg[(b*16+h)*64+dv][2s]   = vr,  [2s+1] = -vi
//        Vswap[(b*16+h)*64+dv][2s]  = vi,  [2s+1] =  vr
//   2: fp32 out + residual: out0=fr, out1=fi (+ resr/resi)
// ---------------------------------------------------------------------------
#define BM 128
#define BN 128
#define BK 32

__device__ __forceinline__ void bgemm_body(
    const ushort* __restrict__ A, const ushort* __restrict__ Bm,
    void* __restrict__ out0, void* __restrict__ out1,
    const float* __restrict__ resr, const float* __restrict__ resi,
    float scale, int mode, int bx, int by)
{
    __shared__ __align__(16) ushort As[BM * BK];
    __shared__ __align__(16) ushort Bs[BN * BK];

    const int tid = threadIdx.x;
    const int lane = tid & 63, wave = tid >> 6;
    const int l15 = lane & 15, quad = lane >> 4;
    const int m0 = by * BM, n0 = bx * BN;
    const int wm = (wave & 1) * 64, wn = (wave >> 1) * 64;

    const int id0 = tid, id1 = 256 + tid;
    const ushort* ga0 = A  + (size_t)(m0 + (id0 >> 2)) * KK + (id0 & 3) * 8;
    const ushort* ga1 = A  + (size_t)(m0 + (id1 >> 2)) * KK + (id1 & 3) * 8;
    const ushort* gb0 = Bm + (size_t)(n0 + (id0 >> 2)) * KK + (id0 & 3) * 8;
    const ushort* gb1 = Bm + (size_t)(n0 + (id1 >> 2)) * KK + (id1 & 3) * 8;
    ushort* la0 = &As[id0 * 8];
    ushort* la1 = &As[id1 * 8];
    ushort* lb0 = &Bs[id0 * 8];
    ushort* lb1 = &Bs[id1 * 8];

    floatx4 acc[4][4];
    #pragma unroll
    for (int fm = 0; fm < 4; ++fm)
        #pragma unroll
        for (int fn = 0; fn < 4; ++fn)
            acc[fm][fn] = (floatx4){0.f, 0.f, 0.f, 0.f};

    for (int k0 = 0; k0 < KK; k0 += BK) {
        gl16(ga0 + k0, la0);
        gl16(ga1 + k0, la1);
        gl16(gb0 + k0, lb0);
        gl16(gb1 + k0, lb1);
        __syncthreads();

        shortx8 af[4], bf[4];
        #pragma unroll
        for (int f = 0; f < 4; ++f)
            af[f] = *(const shortx8*)&As[(wm + f * 16 + l15) * BK + quad * 8];
        #pragma unroll
        for (int f = 0; f < 4; ++f)
            bf[f] = *(const shortx8*)&Bs[(wn + f * 16 + l15) * BK + quad * 8];
        #pragma unroll
        for (int fm = 0; fm < 4; ++fm)
            #pragma unroll
            for (int fn = 0; fn < 4; ++fn)
                acc[fm][fn] = MFMA16(af[fm], bf[fn], acc[fm][fn]);
        __syncthreads();
    }

    // Epilogue. C layout: col = lane&15, row = quad*4 + reg.
    #pragma unroll
    for (int fm = 0; fm < 4; ++fm) {
        #pragma unroll
        for (int fn = 0; fn < 4; ++fn) {
            #pragma unroll
            for (int r = 0; r < 4; ++r) {
                const int m = m0 + wm + fm * 16 + quad * 4 + r;
                const int n = n0 + wn + fn * 16 + l15;
                const float v = acc[fm][fn][r] * scale;
                if (mode == 0) {
                    const int re = n < 1024 ? 0 : 64;
                    const int nn = n & 1023, h = nn >> 6, d = nn & 63;
                    ((ushort*)out0)[(size_t)m * KK + h * 128 + re + d] = f2b(v);
                } else if (mode == 1) {
                    const int nn = n & 1023, h = nn >> 6, dv = nn & 63;
                    const int bb = m >> 10, s = m & 1023;
                    const size_t row = ((size_t)((bb * HH + h) * 64 + dv)) * KK;
                    if (n < 1024) {   // real component vr
                        const ushort g = f2b(v);
                        ((ushort*)out0)[row + 2 * s]     = g;   // Vneg even = vr
                        ((ushort*)out1)[row + 2 * s + 1] = g;   // Vswap odd = vr
                    } else {          // imag component vi
                        ((ushort*)out0)[row + 2 * s + 1] = f2b(-v); // Vneg odd = -vi
                        ((ushort*)out1)[row + 2 * s]     = f2b(v);  // Vswap even = vi
                    }
                } else {
                    const int nn = n & 1023;
                    const size_t off = (size_t)m * 1024 + nn;
                    if (n < 1024) ((float*)out0)[off] = v + resr[off];
                    else          ((float*)out1)[off] = v + resi[off];
                }
            }
        }
    }
}

// merged QKV projection GEMM: blockIdx.z selects {Q, K, V}
__global__ __launch_bounds__(256) void bgemm_qkv(
    const ushort* __restrict__ Xq, const ushort* __restrict__ Xk,
    const ushort* __restrict__ Xv,
    const ushort* __restrict__ Bq, const ushort* __restrict__ Bk,
    const ushort* __restrict__ Bv,
    ushort* __restrict__ qpk, ushort* __restrict__ kpk,
    ushort* __restrict__ Vneg, ushort* __restrict__ Vswp)
{
    const int z = blockIdx.z;
    const ushort* A  = z == 0 ? Xq : z == 1 ? Xk : Xv;
    const ushort* Bm = z == 0 ? Bq : z == 1 ? Bk : Bv;
    void* o0 = z == 0 ? (void*)qpk : z == 1 ? (void*)kpk : (void*)Vneg;
    void* o1 = z == 2 ? (void*)Vswp : nullptr;
    const float sc = z == 0 ? 0.125f : 1.0f;
    const int mode = z == 2 ? 1 : 0;
    bgemm_body(A, Bm, o0, o1, nullptr, nullptr, sc, mode, blockIdx.x, blockIdx.y);
}

// fc GEMM: fp32 out + residual
__global__ __launch_bounds__(256) void bgemm_fc(
    const ushort* __restrict__ A, const ushort* __restrict__ Bm,
    float* __restrict__ fr, float* __restrict__ fi,
    const float* __restrict__ resr, const float* __restrict__ resi)
{
    bgemm_body(A, Bm, fr, fi, resr, resi, 1.0f, 2, blockIdx.x, blockIdx.y);
}

// ---------------------------------------------------------------------------
// Cooperative MFMA attention + exact streamed MagMinMaxNorm, TK=64/iteration.
//   o = (A - mn*P)/(mx - mn);  A = sum attn*v,  P = sum (attn/|attn|)*v
// Block = (32 q rows, h, b); wave (qt_w=w&1, kt_w=w>>1) computes the
// 16q x 32k QK^T subtile; interleaved-complex A/P staged in LDS (pk2 u32).
// LDS is PING-PONG double-buffered (it&1) so only ONE barrier per 64-k
// iteration is needed (write -> barrier -> read; ping-pong protects reads
// of iteration it-1 from writes of iteration it+1 via the barrier at it).
// Layout is XOR-swizzled: word (row, col ^ ((row&7)<<2)) in a 32x32 tile.
//   writes (col = kt2*16+l15, row = qt_w*16+quad*4+r): 2-way banked = free
//   b128 AV reads (row = q2*16+l15, col = quad*4 chunks): uniform 8/bank =
//   conflict-free minimum for wave64 ds_read_b128.
// AV: each wave owns 16 dv columns, contracts all 64 k per iteration.
// Output: bf16 pack xo[m][2048] = [o_r (h*64+dv) | o_i].
// ---------------------------------------------------------------------------
#define SWZ(row, col) (((row) << 5) + ((col) ^ (((row) & 7) << 2)))

__global__ __launch_bounds__(256) void attn_mfma(
    const ushort* __restrict__ qpk, const ushort* __restrict__ kpk,
    const ushort* __restrict__ vn, const ushort* __restrict__ vs,
    ushort* __restrict__ xo)
{
    __shared__ unsigned Abuf[2][2][32 * 32];   // [pingpong][k-half][32q x 32k]
    __shared__ unsigned Pbuf[2][2][32 * 32];
    __shared__ unsigned mnb[32], mxb[32];

    const int tid  = threadIdx.x;
    const int wave = tid >> 6, lane = tid & 63;
    const int l15  = lane & 15, quad = lane >> 4;
    const int qt_w = wave & 1, kt_w = wave >> 1;
    const int qt = blockIdx.x, h = blockIdx.y, b = blockIdx.z;
    const size_t qrow0 = (size_t)b * SS + (size_t)qt * 32;

    if (tid < 32) { mnb[tid] = 0x7f800000u; mxb[tid] = 0u; }

    // Q fragments (A-operand), with pre-negated imag copies
    const ushort* qb = qpk + (qrow0 + qt_w * 16 + l15) * KK + h * 128 + quad * 8;
    shortx8 Aq0 = *(const shortx8*)(qb);
    shortx8 Aq1 = *(const shortx8*)(qb + 32);
    shortx8 Aq2 = *(const shortx8*)(qb + 64);
    shortx8 Aq3 = *(const shortx8*)(qb + 96);
    shortx8 Nq2 = negf(Aq2), Nq3 = negf(Aq3);

    // K rows for this wave's 32-k half of each 64-k iteration
    const ushort* kb = kpk + ((size_t)b * SS + kt_w * 32 + l15) * KK + h * 128 + quad * 8;
    // V pack rows: this wave's 16 dv columns
    const size_t vrow = ((size_t)((b * HH + h) * 64) + wave * 16 + l15) * KK + quad * 8;
    const ushort* vnb = vn + vrow;
    const ushort* vsb = vs + vrow;

    floatx4 acc[2][4];   // [q-half][Ar,Ai,Pr,Pi]
    #pragma unroll
    for (int q2 = 0; q2 < 2; ++q2)
        #pragma unroll
        for (int j = 0; j < 4; ++j)
            acc[q2][j] = (floatx4){0.f, 0.f, 0.f, 0.f};
    float rmn[4] = {1e30f, 1e30f, 1e30f, 1e30f};
    float rmx[4] = {0.f, 0.f, 0.f, 0.f};

    for (int it = 0; it < 16; ++it) {
        const int p = it & 1;
        unsigned* Ab = Abuf[p][kt_w];
        unsigned* Pb = Pbuf[p][kt_w];

        // ---- issue ALL global fragment loads for this iteration up front ----
        const ushort* k0 = kb + (size_t)(it * 64) * KK;
        shortx8 Kf[2][4];
        #pragma unroll
        for (int kt2 = 0; kt2 < 2; ++kt2)
            #pragma unroll
            for (int f = 0; f < 4; ++f)
                Kf[kt2][f] = *(const shortx8*)(k0 + (size_t)(kt2 * 16) * KK + f * 32);
        shortx8 Vn_[4], Vs_[4];
        #pragma unroll
        for (int f = 0; f < 4; ++f) {
            Vn_[f] = *(const shortx8*)(vnb + it * 128 + f * 32);
            Vs_[f] = *(const shortx8*)(vsb + it * 128 + f * 32);
        }

        // ---- QK^T: 16q x 32k for this wave ----
        floatx4 cr[2], ci[2];
        #pragma unroll
        for (int kt2 = 0; kt2 < 2; ++kt2) {
            floatx4 r_ = (floatx4){0.f,0.f,0.f,0.f};
            floatx4 i_ = (floatx4){0.f,0.f,0.f,0.f};
            r_ = MFMA16(Aq0, Kf[kt2][0], r_); r_ = MFMA16(Aq1, Kf[kt2][1], r_);
            r_ = MFMA16(Nq2, Kf[kt2][2], r_); r_ = MFMA16(Nq3, Kf[kt2][3], r_);
            i_ = MFMA16(Aq2, Kf[kt2][0], i_); i_ = MFMA16(Aq3, Kf[kt2][1], i_);
            i_ = MFMA16(Aq0, Kf[kt2][2], i_); i_ = MFMA16(Aq1, Kf[kt2][3], i_);
            cr[kt2] = r_; ci[kt2] = i_;
        }

        // ---- magnitude, phase, packed LDS writes (ping-pong: no barrier) ----
        #pragma unroll
        for (int kt2 = 0; kt2 < 2; ++kt2) {
            #pragma unroll
            for (int r = 0; r < 4; ++r) {
                const float ar = cr[kt2][r], ai = ci[kt2][r];
                const float s2 = fmaf(ar, ar, ai * ai);
                const float irm = s2 > 0.f ? rsqrtf(s2) : 0.f;
                const float mag = s2 * irm;
                rmn[r] = fminf(rmn[r], mag);
                rmx[r] = fmaxf(rmx[r], mag);
                const int row = qt_w * 16 + quad * 4 + r;
                const int w = SWZ(row, kt2 * 16 + l15);
                Ab[w] = pk2(ar, ai);
                Pb[w] = pk2(ar * irm, ai * irm);
            }
        }
        __syncthreads();   // writes visible to all waves

        // ---- AV: contract 64 k for both 16-q halves, this wave's 16 dv ----
        const unsigned* A0 = Abuf[p][0];
        const unsigned* A1 = Abuf[p][1];
        const unsigned* P0 = Pbuf[p][0];
        const unsigned* P1 = Pbuf[p][1];
        __builtin_amdgcn_s_setprio(1);
        #pragma unroll
        for (int q2 = 0; q2 < 2; ++q2) {
            const int row = q2 * 16 + l15;
            const int rb = row * 32, rm = (row & 7) << 2;
            const int c0 = rb + ((quad * 4) ^ rm);
            const int c1 = rb + ((16 + quad * 4) ^ rm);
            shortx8 Af0 = *(const shortx8*)&A0[c0];
            shortx8 Af1 = *(const shortx8*)&A0[c1];
            shortx8 Af2 = *(const shortx8*)&A1[c0];
            shortx8 Af3 = *(const shortx8*)&A1[c1];
            shortx8 Pf0 = *(const shortx8*)&P0[c0];
            shortx8 Pf1 = *(const shortx8*)&P0[c1];
            shortx8 Pf2 = *(const shortx8*)&P1[c0];
            shortx8 Pf3 = *(const shortx8*)&P1[c1];
            acc[q2][0] = MFMA16(Af0, Vn_[0], acc[q2][0]);
            acc[q2][0] = MFMA16(Af1, Vn_[1], acc[q2][0]);
            acc[q2][0] = MFMA16(Af2, Vn_[2], acc[q2][0]);
            acc[q2][0] = MFMA16(Af3, Vn_[3], acc[q2][0]);
            acc[q2][1] = MFMA16(Af0, Vs_[0], acc[q2][1]);
            acc[q2][1] = MFMA16(Af1, Vs_[1], acc[q2][1]);
            acc[q2][1] = MFMA16(Af2, Vs_[2], acc[q2][1]);
            acc[q2][1] = MFMA16(Af3, Vs_[3], acc[q2][1]);
            acc[q2][2] = MFMA16(Pf0, Vn_[0], acc[q2][2]);
            acc[q2][2] = MFMA16(Pf1, Vn_[1], acc[q2][2]);
            acc[q2][2] = MFMA16(Pf2, Vn_[2], acc[q2][2]);
            acc[q2][2] = MFMA16(Pf3, Vn_[3], acc[q2][2]);
            acc[q2][3] = MFMA16(Pf0, Vs_[0], acc[q2][3]);
            acc[q2][3] = MFMA16(Pf1, Vs_[1], acc[q2][3]);
            acc[q2][3] = MFMA16(Pf2, Vs_[2], acc[q2][3]);
            acc[q2][3] = MFMA16(Pf3, Vs_[3], acc[q2][3]);
        }
        __builtin_amdgcn_s_setprio(0);
        // no trailing barrier: next iteration writes the other ping-pong half
    }

    // ---- per-row min/max: 16-lane shuffle, then cross-wave LDS atomics ----
    #pragma unroll
    for (int r = 0; r < 4; ++r) {
        float mn = rmn[r], mx = rmx[r];
        #pragma unroll
        for (int o = 1; o < 16; o <<= 1) {
            mn = fminf(mn, __shfl_xor(mn, o));
            mx = fmaxf(mx, __shfl_xor(mx, o));
        }
        if (l15 == 0) {
            const int q = qt_w * 16 + quad * 4 + r;
            atomicMin(&mnb[q], __float_as_uint(mn));   // mag >= 0: bits monotone
            atomicMax(&mxb[q], __float_as_uint(mx));
        }
    }
    __syncthreads();

    // ---- epilogue: o = (A - mn*P)/(mx - mn) -> bf16 pack ----
    #pragma unroll
    for (int q2 = 0; q2 < 2; ++q2) {
        #pragma unroll
        for (int r = 0; r < 4; ++r) {
            const int q = q2 * 16 + quad * 4 + r;
            const float mn = __uint_as_float(mnb[q]);
            const float mx = __uint_as_float(mxb[q]);
            const float d = mx - mn;
            const float invd = d > 0.f ? 1.f / d : 0.f;
            const float vr_ = (acc[q2][0][r] - mn * acc[q2][2][r]) * invd;
            const float vi_ = (acc[q2][1][r] - mn * acc[q2][3][r]) * invd;
            const size_t row = (qrow0 + q) * KK + h * 64 + wave * 16 + l15;
            xo[row]        = f2b(vr_);
            xo[row + 1024] = f2b(vi_);
        }
    }
}

// ---------------------------------------------------------------------------
// Complex covariance-whitening layernorm, one wave per (b,s) row.
// ---------------------------------------------------------------------------
__global__ __launch_bounds__(256) void ln_kernel(
    const float* __restrict__ xr, const float* __restrict__ xi,
    const float* __restrict__ g_rr, const float* __restrict__ g_ri,
    const float* __restrict__ g_ii,
    const float* __restrict__ b_r, const float* __restrict__ b_i,
    float* __restrict__ out)
{
    const int lane = threadIdx.x & 63;
    const int wave = threadIdx.x >> 6;
    const int row  = blockIdx.x * 4 + wave;
    const float* pr = xr + (size_t)row * DD;
    const float* pi = xi + (size_t)row * DD;

    float r[16], im[16];
    float sr = 0.f, si = 0.f;
    #pragma unroll
    for (int j = 0; j < 16; ++j) {
        r[j]  = pr[lane + 64*j];
        im[j] = pi[lane + 64*j];
        sr += r[j]; si += im[j];
    }
    #pragma unroll
    for (int o = 32; o; o >>= 1) { sr += __shfl_xor(sr, o); si += __shfl_xor(si, o); }
    const float mr = sr * (1.f / DD), mi = si * (1.f / DD);

    float srr = 0.f, sii = 0.f, sri = 0.f;
    #pragma unroll
    for (int j = 0; j < 16; ++j) {
        const float a = r[j] - mr, c = im[j] - mi;
        srr = fmaf(a, a, srr); sii = fmaf(c, c, sii); sri = fmaf(a, c, sri);
    }
    #pragma unroll
    for (int o = 32; o; o >>= 1) {
        srr += __shfl_xor(srr, o); sii += __shfl_xor(sii, o); sri += __shfl_xor(sri, o);
    }
    const float Vrr = srr * (1.f / DD) + EPS_LN;
    const float Vii = sii * (1.f / DD) + EPS_LN;
    const float Vri = sri * (1.f / DD);
    const float s  = sqrtf(Vrr * Vii - Vri * Vri);
    const float t  = sqrtf(Vrr + Vii + 2.f * s);
    const float inv = 1.f / (s * t);
    const float Wrr = (Vii + s) * inv;
    const float Wii = (Vrr + s) * inv;
    const float Wri = -Vri * inv;

    #pragma unroll
    for (int j = 0; j < 16; ++j) {
        const int d = lane + 64*j;
        const float a = r[j] - mr, c = im[j] - mi;
        const float or_ = Wrr * a + Wri * c;
        const float oi_ = Wri * a + Wii * c;
        out[(size_t)row * DD + d] = g_rr[d]*or_ + g_ri[d]*oi_ + b_r[d];
        out[(size_t)(M_ROWS) * DD + (size_t)row * DD + d] = g_ri[d]*or_ + g_ii[d]*oi_ + b_i[d];
    }
}

// ---------------------------------------------------------------------------
extern "C" void kernel_launch(void* const* d_in, const int* in_sizes, int n_in,
                              void* d_out, int out_size, void* d_ws, size_t ws_size,
                              hipStream_t stream) {
    const float* q_r  = (const float*)d_in[0];
    const float* q_i  = (const float*)d_in[1];
    const float* k_r  = (const float*)d_in[2];
    const float* k_i  = (const float*)d_in[3];
    const float* v_r  = (const float*)d_in[4];
    const float* v_i  = (const float*)d_in[5];
    const float* wq_r = (const float*)d_in[6];
    const float* wq_i = (const float*)d_in[7];
    const float* wk_r = (const float*)d_in[8];
    const float* wk_i = (const float*)d_in[9];
    const float* wv_r = (const float*)d_in[10];
    const float* wv_i = (const float*)d_in[11];
    const float* fc_r = (const float*)d_in[12];
    const float* fc_i = (const float*)d_in[13];
    const float* g_rr = (const float*)d_in[14];
    const float* g_ri = (const float*)d_in[15];
    const float* g_ii = (const float*)d_in[16];
    const float* b_r  = (const float*)d_in[17];
    const float* b_i  = (const float*)d_in[18];
    float* out = (float*)d_out;

    // Workspace: 7 units of 16 MiB = 112 MiB.
    float* ws = (float*)d_ws;
    const size_t NE = (size_t)M_ROWS * 1024;        // 4M floats = 16 MiB
    ushort* Xq   = (ushort*)(ws + 0 * NE);          // u0; later Vneg
    ushort* Xk   = (ushort*)(ws + 1 * NE);          // u1; later Vswap
    ushort* Xv   = (ushort*)(ws + 2 * NE);          // u2; later xo
    ushort* qpk  = (ushort*)(ws + 3 * NE);          // u3; later fr
    ushort* kpk  = (ushort*)(ws + 4 * NE);          // u4; later fi
    ushort* Bq   = (ushort*)(ws + 5 * NE);          // u5 lo
    ushort* Bk   = Bq + (size_t)KK * KK;            // u5 hi
    ushort* Bv   = (ushort*)(ws + 6 * NE);          // u6 lo
    ushort* Bf   = Bv + (size_t)KK * KK;            // u6 hi
    ushort* Vneg = (ushort*)(ws + 0 * NE);          // aliases dead Xq
    ushort* Vswp = (ushort*)(ws + 1 * NE);          // aliases dead Xk
    ushort* xo   = (ushort*)(ws + 2 * NE);          // aliases dead Xv
    float*  fr   = ws + 3 * NE;                     // aliases dead qpk
    float*  fi   = ws + 4 * NE;                     // aliases dead kpk

    // bf16 operand packing
    pack_x<<<dim3(4096, 3), 256, 0, stream>>>(q_r, q_i, k_r, k_i, v_r, v_i, Xq, Xk, Xv);
    pack_w<<<dim3(1024, 4), 256, 0, stream>>>(wq_r, wq_i, wk_r, wk_i, wv_r, wv_i,
                                              fc_r, fc_i, Bq, Bk, Bv, Bf);

    // merged QKV projections (q gets 1/sqrt(DK) folded in): 1536 blocks
    bgemm_qkv<<<dim3(KK / BN, M_ROWS / BM, 3), 256, 0, stream>>>(
        Xq, Xk, Xv, Bq, Bk, Bv, qpk, kpk, Vneg, Vswp);

    // cooperative MFMA attention + MagMinMaxNorm -> bf16 [4096][2048] pack
    attn_mfma<<<dim3(SS / 32, HH, BB), 256, 0, stream>>>(qpk, kpk, Vneg, Vswp, xo);

    // output projection + residual (bf16 MFMA, fp32 out)
    bgemm_fc<<<dim3(KK / BN, M_ROWS / BM), 256, 0, stream>>>(xo, Bf, fr, fi, q_r, q_i);

    // complex layernorm -> d_out [2,B,S,D]
    ln_kernel<<<M_ROWS / 4, 256, 0, stream>>>(fr, fi, g_rr, g_ri, g_ii, b_r, b_i, out);
}

// Round 2
// 526.675 us; speedup vs baseline: 1.2392x; 1.2392x over previous
//
#include <hip/hip_runtime.h>
#include <hip/hip_bf16.h>

// Problem constants
#define BB 4
#define SS 1024
#define DD 1024
#define HH 16
#define DKH 64
#define EPS_LN 1e-6f

#define M_ROWS 4096   // B*S
#define KK 2048       // concatenated complex K (re|im)

typedef float  floatx4 __attribute__((ext_vector_type(4)));
typedef short  shortx8 __attribute__((ext_vector_type(8)));
#define MFMA16(a, b, c) __builtin_amdgcn_mfma_f32_16x16x32_bf16(a, b, c, 0, 0, 0)

// pack two floats into one u32 of 2 bf16 (low = first) via single HW op (RNE)
__device__ __forceinline__ unsigned pk2(float lo, float hi) {
    unsigned u;
    asm("v_cvt_pk_bf16_f32 %0, %1, %2" : "=v"(u) : "v"(lo), "v"(hi));
    return u;
}

// float -> bf16 (RNE) via the same HW op
__device__ __forceinline__ ushort f2b(float x) {
    return (ushort)(pk2(x, x) & 0xffffu);
}

// negate a bf16x8 fragment (flip sign bits)
__device__ __forceinline__ shortx8 negf(shortx8 x) {
    shortx8 r;
    #pragma unroll
    for (int i = 0; i < 8; ++i) r[i] = (short)(x[i] ^ (short)0x8000);
    return r;
}

// per-32-bit-word [lo=vr, hi=-vi] -> [lo=vi, hi=vr]  (rotate16 + flip lo sign)
__device__ __forceinline__ shortx8 vswap(shortx8 v) {
    union { shortx8 s; unsigned u[4]; } a, b;
    a.s = v;
    #pragma unroll
    for (int i = 0; i < 4; ++i) {
        const unsigned w = a.u[i];
        b.u[i] = ((w >> 16) | (w << 16)) ^ 0x00008000u;
    }
    return b.s;
}

// async global->LDS, 16 bytes per lane (lane-contiguous LDS layout required)
__device__ __forceinline__ void gl16(const void* g, void* l) {
    __builtin_amdgcn_global_load_lds(
        (const __attribute__((address_space(1))) unsigned int*)g,
        (__attribute__((address_space(3))) unsigned int*)l, 16, 0, 0);
}

// ---------------------------------------------------------------------------
// pack_x: [4096][1024] fp32 pair -> [4096][2048] bf16  (row = [re | im])
// ---------------------------------------------------------------------------
__global__ __launch_bounds__(256) void pack_x(
    const float* __restrict__ qr, const float* __restrict__ qi,
    const float* __restrict__ kr, const float* __restrict__ ki,
    const float* __restrict__ vr, const float* __restrict__ vi,
    ushort* __restrict__ Xq, ushort* __restrict__ Xk, ushort* __restrict__ Xv)
{
    const int t = blockIdx.y;
    const float* pr = t == 0 ? qr : t == 1 ? kr : vr;
    const float* pi = t == 0 ? qi : t == 1 ? ki : vi;
    ushort* X = t == 0 ? Xq : t == 1 ? Xk : Xv;
    const int idx = blockIdx.x * 256 + threadIdx.x;
    const int row = idx >> 8, c4 = (idx & 255) * 4;
    float4 a = *(const float4*)(pr + (size_t)row * 1024 + c4);
    float4 b = *(const float4*)(pi + (size_t)row * 1024 + c4);
    ushort4 ua; ua.x = f2b(a.x); ua.y = f2b(a.y); ua.z = f2b(a.z); ua.w = f2b(a.w);
    ushort4 ub; ub.x = f2b(b.x); ub.y = f2b(b.y); ub.z = f2b(b.z); ub.w = f2b(b.w);
    *(ushort4*)(X + (size_t)row * KK + c4)        = ua;
    *(ushort4*)(X + (size_t)row * KK + 1024 + c4) = ub;
}

// ---------------------------------------------------------------------------
// pack_w: [1024][1024] fp32 pair -> [2048][2048] bf16
//   row n       = [ wr[n] | -wi[n] ]   (produces Yr)
//   row 1024+n  = [ wi[n] |  wr[n] ]   (produces Yi)
// ---------------------------------------------------------------------------
__global__ __launch_bounds__(256) void pack_w(
    const float* __restrict__ ar, const float* __restrict__ ai,
    const float* __restrict__ br, const float* __restrict__ bi,
    const float* __restrict__ cr, const float* __restrict__ ci,
    const float* __restrict__ dr, const float* __restrict__ di,
    ushort* __restrict__ Bq, ushort* __restrict__ Bk,
    ushort* __restrict__ Bv, ushort* __restrict__ Bf)
{
    const int t = blockIdx.y;
    const float* wr = t == 0 ? ar : t == 1 ? br : t == 2 ? cr : dr;
    const float* wi = t == 0 ? ai : t == 1 ? bi : t == 2 ? ci : di;
    ushort* Bo = t == 0 ? Bq : t == 1 ? Bk : t == 2 ? Bv : Bf;
    const int idx = blockIdx.x * 256 + threadIdx.x;
    const int n = idx >> 8, c4 = (idx & 255) * 4;
    float4 a = *(const float4*)(wr + (size_t)n * 1024 + c4);
    float4 b = *(const float4*)(wi + (size_t)n * 1024 + c4);
    ushort4 ua; ua.x = f2b(a.x);  ua.y = f2b(a.y);  ua.z = f2b(a.z);  ua.w = f2b(a.w);
    ushort4 ub; ub.x = f2b(b.x);  ub.y = f2b(b.y);  ub.z = f2b(b.z);  ub.w = f2b(b.w);
    ushort4 un; un.x = f2b(-b.x); un.y = f2b(-b.y); un.z = f2b(-b.z); un.w = f2b(-b.w);
    *(ushort4*)(Bo + (size_t)n * KK + c4)                 = ua;
    *(ushort4*)(Bo + (size_t)n * KK + 1024 + c4)          = un;
    *(ushort4*)(Bo + (size_t)(1024 + n) * KK + c4)        = ub;
    *(ushort4*)(Bo + (size_t)(1024 + n) * KK + 1024 + c4) = ua;
}

// ---------------------------------------------------------------------------
// bf16 MFMA GEMM body (m97 recipe): C[M, N=2048] = A[M,2048] . B[N,2048]^T
// Epilogue modes (fragment-major packs so attn loads are lane-coalesced):
//   0: Q frag pack  [b][h][qt(32x 32rows)][qhalf*4+f][lane*8]
//   3: K frag pack  [b][h][t(16x 64rows)][(row>>4)*4+f][lane*8]
//   1: V frag pack  [b][h][((it*4+w)*4+f)][lane*8], interleaved [vr,-vi]
//   2: fp32 out + residual: out0=fr, out1=fi (+ resr/resi)
// ---------------------------------------------------------------------------
#define BM 128
#define BN 128
#define BK 32

__device__ __forceinline__ void bgemm_body(
    const ushort* __restrict__ A, const ushort* __restrict__ Bm,
    void* __restrict__ out0, void* __restrict__ out1,
    const float* __restrict__ resr, const float* __restrict__ resi,
    float scale, int mode, int bx, int by)
{
    __shared__ __align__(16) ushort As[BM * BK];
    __shared__ __align__(16) ushort Bs[BN * BK];

    const int tid = threadIdx.x;
    const int lane = tid & 63, wave = tid >> 6;
    const int l15 = lane & 15, quad = lane >> 4;
    const int m0 = by * BM, n0 = bx * BN;
    const int wm = (wave & 1) * 64, wn = (wave >> 1) * 64;

    const int id0 = tid, id1 = 256 + tid;
    const ushort* ga0 = A  + (size_t)(m0 + (id0 >> 2)) * KK + (id0 & 3) * 8;
    const ushort* ga1 = A  + (size_t)(m0 + (id1 >> 2)) * KK + (id1 & 3) * 8;
    const ushort* gb0 = Bm + (size_t)(n0 + (id0 >> 2)) * KK + (id0 & 3) * 8;
    const ushort* gb1 = Bm + (size_t)(n0 + (id1 >> 2)) * KK + (id1 & 3) * 8;
    ushort* la0 = &As[id0 * 8];
    ushort* la1 = &As[id1 * 8];
    ushort* lb0 = &Bs[id0 * 8];
    ushort* lb1 = &Bs[id1 * 8];

    floatx4 acc[4][4];
    #pragma unroll
    for (int fm = 0; fm < 4; ++fm)
        #pragma unroll
        for (int fn = 0; fn < 4; ++fn)
            acc[fm][fn] = (floatx4){0.f, 0.f, 0.f, 0.f};

    for (int k0 = 0; k0 < KK; k0 += BK) {
        gl16(ga0 + k0, la0);
        gl16(ga1 + k0, la1);
        gl16(gb0 + k0, lb0);
        gl16(gb1 + k0, lb1);
        __syncthreads();

        shortx8 af[4], bf[4];
        #pragma unroll
        for (int f = 0; f < 4; ++f)
            af[f] = *(const shortx8*)&As[(wm + f * 16 + l15) * BK + quad * 8];
        #pragma unroll
        for (int f = 0; f < 4; ++f)
            bf[f] = *(const shortx8*)&Bs[(wn + f * 16 + l15) * BK + quad * 8];
        #pragma unroll
        for (int fm = 0; fm < 4; ++fm)
            #pragma unroll
            for (int fn = 0; fn < 4; ++fn)
                acc[fm][fn] = MFMA16(af[fm], bf[fn], acc[fm][fn]);
        __syncthreads();
    }

    // Epilogue. C layout: col = lane&15, row = quad*4 + reg.
    #pragma unroll
    for (int fm = 0; fm < 4; ++fm) {
        #pragma unroll
        for (int fn = 0; fn < 4; ++fn) {
            #pragma unroll
            for (int r = 0; r < 4; ++r) {
                const int m = m0 + wm + fm * 16 + quad * 4 + r;
                const int n = n0 + wn + fn * 16 + l15;
                const float v = acc[fm][fn][r] * scale;
                const int nn = n & 1023;
                const int hh = nn >> 6;
                const int bb = m >> 10, s = m & 1023;
                if (mode == 0) {           // Q fragment pack (32-row tiles)
                    const int dk = (n < 1024 ? 0 : 64) + (nn & 63);
                    const int tq = s >> 5, row = s & 31;
                    ushort* Qb = (ushort*)out0 +
                        ((size_t)(bb * HH + hh) * 32 + tq) * 4096;
                    const int off = ((row >> 4) * 4 + (dk >> 5)) * 512 +
                                    ((dk >> 3) & 3) * 128 + (row & 15) * 8 + (dk & 7);
                    Qb[off] = f2b(v);
                } else if (mode == 3) {    // K fragment pack (64-row tiles)
                    const int dk = (n < 1024 ? 0 : 64) + (nn & 63);
                    const int t = s >> 6, row = s & 63;
                    ushort* Kb = (ushort*)out0 +
                        ((size_t)(bb * HH + hh) * 16 + t) * 8192;
                    const int off = ((row >> 4) * 4 + (dk >> 5)) * 512 +
                                    ((dk >> 3) & 3) * 128 + (row & 15) * 8 + (dk & 7);
                    Kb[off] = f2b(v);
                } else if (mode == 1) {    // V fragment pack, interleaved [vr,-vi]
                    const int dv = nn & 63;
                    const int c = 2 * s + (n < 1024 ? 0 : 1);
                    ushort* Vb = (ushort*)out0 + (size_t)(bb * HH + hh) * 131072;
                    const int off = (((c >> 7) * 4 + (dv >> 4)) * 4 + ((c >> 5) & 3)) * 512 +
                                    ((c >> 3) & 3) * 128 + (dv & 15) * 8 + (c & 7);
                    Vb[off] = f2b(n < 1024 ? v : -v);
                } else {                   // fc: fp32 out + residual
                    const size_t off = (size_t)m * 1024 + nn;
                    if (n < 1024) ((float*)out0)[off] = v + resr[off];
                    else          ((float*)out1)[off] = v + resi[off];
                }
            }
        }
    }
}

// Q/K projection GEMMs: blockIdx.z selects {Q, K}
__global__ __launch_bounds__(256) void bgemm_qk(
    const ushort* __restrict__ Xq, const ushort* __restrict__ Xk,
    const ushort* __restrict__ Bq, const ushort* __restrict__ Bk,
    ushort* __restrict__ qpk, ushort* __restrict__ kpk)
{
    const int z = blockIdx.z;
    bgemm_body(z == 0 ? Xq : Xk, z == 0 ? Bq : Bk,
               z == 0 ? (void*)qpk : (void*)kpk, nullptr, nullptr, nullptr,
               z == 0 ? 0.125f : 1.0f, z == 0 ? 0 : 3, blockIdx.x, blockIdx.y);
}

// V projection GEMM (separate dispatch: its output aliases dead Xq)
__global__ __launch_bounds__(256) void bgemm_v(
    const ushort* __restrict__ Xv, const ushort* __restrict__ Bv,
    ushort* __restrict__ Vneg)
{
    bgemm_body(Xv, Bv, (void*)Vneg, nullptr, nullptr, nullptr,
               1.0f, 1, blockIdx.x, blockIdx.y);
}

// fc GEMM: fp32 out + residual
__global__ __launch_bounds__(256) void bgemm_fc(
    const ushort* __restrict__ A, const ushort* __restrict__ Bm,
    float* __restrict__ fr, float* __restrict__ fi,
    const float* __restrict__ resr, const float* __restrict__ resi)
{
    bgemm_body(A, Bm, fr, fi, resr, resi, 1.0f, 2, blockIdx.x, blockIdx.y);
}

// ---------------------------------------------------------------------------
// Cooperative MFMA attention + exact streamed MagMinMaxNorm, TK=64/iteration.
//   o = (A - mn*P)/(mx - mn);  A = sum attn*v,  P = sum (attn/|attn|)*v
// All Q/K/V global loads are lane-coalesced (fragment-major packs).
// K is register double-buffered (prefetch it+1 under mag+AV of it); V loaded
// at iteration top (consumed after the barrier). Vswap fragments derived
// in-register from Vneg (rotate16 + sign flip). Per-iteration barrier is
// lgkmcnt(0)-only so global prefetch loads stay in flight across it.
// LDS A/P ping-pong (it&1), XOR-swizzled (conflict-free writes & b128 reads).
// 1-D grid, XCD-contiguous swizzle: each XCD owns 8 whole (b,h) groups so
// K/V working set (~4 MB) stays in one XCD's L2.
// Output: bf16 pack xo[m][2048] = [o_r (h*64+dv) | o_i].
// ---------------------------------------------------------------------------
#define SWZ(row, col) (((row) << 5) + ((col) ^ (((row) & 7) << 2)))

__device__ __forceinline__ void loadK(shortx8 (&K)[2][4], const ushort* kfb,
                                      int t, int kt_w) {
    #pragma unroll
    for (int kt2 = 0; kt2 < 2; ++kt2)
        #pragma unroll
        for (int f = 0; f < 4; ++f)
            K[kt2][f] = *(const shortx8*)(kfb + t * 8192 +
                                          ((kt_w * 2 + kt2) * 4 + f) * 512);
}

__device__ __forceinline__ void loadVn(shortx8 (&V)[4], const ushort* vfb,
                                       int t, int wave) {
    #pragma unroll
    for (int f = 0; f < 4; ++f)
        V[f] = *(const shortx8*)(vfb + ((t * 4 + wave) * 4 + f) * 512);
}

#define ATTN_ITER(IT, NX, KC, KN)                                             \
  {                                                                           \
    loadVn(V_, vfb, (IT), wave);                                              \
    const int p_ = (IT) & 1;                                                  \
    unsigned* Ab = Abuf[p_][kt_w];                                            \
    unsigned* Pb = Pbuf[p_][kt_w];                                            \
    floatx4 cr[2], ci[2];                                                     \
    _Pragma("unroll")                                                         \
    for (int kt2 = 0; kt2 < 2; ++kt2) {                                       \
      floatx4 r_ = (floatx4){0.f, 0.f, 0.f, 0.f};                             \
      floatx4 i_ = (floatx4){0.f, 0.f, 0.f, 0.f};                             \
      r_ = MFMA16(Aq0, KC[kt2][0], r_); r_ = MFMA16(Aq1, KC[kt2][1], r_);     \
      r_ = MFMA16(Nq2, KC[kt2][2], r_); r_ = MFMA16(Nq3, KC[kt2][3], r_);     \
      i_ = MFMA16(Aq2, KC[kt2][0], i_); i_ = MFMA16(Aq3, KC[kt2][1], i_);     \
      i_ = MFMA16(Aq0, KC[kt2][2], i_); i_ = MFMA16(Aq1, KC[kt2][3], i_);     \
      cr[kt2] = r_; ci[kt2] = i_;                                             \
    }                                                                         \
    loadK(KN, kfb, (NX), kt_w);                                               \
    _Pragma("unroll")                                                         \
    for (int kt2 = 0; kt2 < 2; ++kt2) {                                       \
      _Pragma("unroll")                                                       \
      for (int r = 0; r < 4; ++r) {                                           \
        const float ar = cr[kt2][r], ai = ci[kt2][r];                         \
        const float s2 = fmaf(ar, ar, ai * ai);                               \
        const float irm = s2 > 0.f ? rsqrtf(s2) : 0.f;                        \
        const float mag = s2 * irm;                                           \
        rmn[r] = fminf(rmn[r], mag);                                          \
        rmx[r] = fmaxf(rmx[r], mag);                                          \
        const int row_ = qt_w * 16 + quad * 4 + r;                            \
        const int w_ = SWZ(row_, kt2 * 16 + l15);                             \
        Ab[w_] = pk2(ar, ai);                                                 \
        Pb[w_] = pk2(ar * irm, ai * irm);                                     \
      }                                                                       \
    }                                                                         \
    asm volatile("s_waitcnt lgkmcnt(0)" ::: "memory");                        \
    __builtin_amdgcn_s_barrier();                                             \
    const shortx8 Vs0 = vswap(V_[0]), Vs1 = vswap(V_[1]);                     \
    const shortx8 Vs2 = vswap(V_[2]), Vs3 = vswap(V_[3]);                     \
    const unsigned* A0 = Abuf[p_][0];                                         \
    const unsigned* A1 = Abuf[p_][1];                                         \
    const unsigned* P0 = Pbuf[p_][0];                                         \
    const unsigned* P1 = Pbuf[p_][1];                                         \
    __builtin_amdgcn_s_setprio(1);                                            \
    _Pragma("unroll")                                                         \
    for (int q2 = 0; q2 < 2; ++q2) {                                          \
      const int row_ = q2 * 16 + l15;                                         \
      const int rb_ = row_ * 32, rm_ = (row_ & 7) << 2;                       \
      const int c0_ = rb_ + ((quad * 4) ^ rm_);                               \
      const int c1_ = rb_ + ((16 + quad * 4) ^ rm_);                          \
      shortx8 Af0 = *(const shortx8*)&A0[c0_];                                \
      shortx8 Af1 = *(const shortx8*)&A0[c1_];                                \
      shortx8 Af2 = *(const shortx8*)&A1[c0_];                                \
      shortx8 Af3 = *(const shortx8*)&A1[c1_];                                \
      shortx8 Pf0 = *(const shortx8*)&P0[c0_];                                \
      shortx8 Pf1 = *(const shortx8*)&P0[c1_];                                \
      shortx8 Pf2 = *(const shortx8*)&P1[c0_];                                \
      shortx8 Pf3 = *(const shortx8*)&P1[c1_];                                \
      acc[q2][0] = MFMA16(Af0, V_[0], acc[q2][0]);                            \
      acc[q2][0] = MFMA16(Af1, V_[1], acc[q2][0]);                            \
      acc[q2][0] = MFMA16(Af2, V_[2], acc[q2][0]);                            \
      acc[q2][0] = MFMA16(Af3, V_[3], acc[q2][0]);                            \
      acc[q2][1] = MFMA16(Af0, Vs0, acc[q2][1]);                              \
      acc[q2][1] = MFMA16(Af1, Vs1, acc[q2][1]);                              \
      acc[q2][1] = MFMA16(Af2, Vs2, acc[q2][1]);                              \
      acc[q2][1] = MFMA16(Af3, Vs3, acc[q2][1]);                              \
      acc[q2][2] = MFMA16(Pf0, V_[0], acc[q2][2]);                            \
      acc[q2][2] = MFMA16(Pf1, V_[1], acc[q2][2]);                            \
      acc[q2][2] = MFMA16(Pf2, V_[2], acc[q2][2]);                            \
      acc[q2][2] = MFMA16(Pf3, V_[3], acc[q2][2]);                            \
      acc[q2][3] = MFMA16(Pf0, Vs0, acc[q2][3]);                              \
      acc[q2][3] = MFMA16(Pf1, Vs1, acc[q2][3]);                              \
      acc[q2][3] = MFMA16(Pf2, Vs2, acc[q2][3]);                              \
      acc[q2][3] = MFMA16(Pf3, Vs3, acc[q2][3]);                              \
    }                                                                         \
    __builtin_amdgcn_s_setprio(0);                                            \
  }

__global__ __launch_bounds__(256) void attn_mfma(
    const ushort* __restrict__ qpk, const ushort* __restrict__ kpk,
    const ushort* __restrict__ vn, ushort* __restrict__ xo)
{
    __shared__ unsigned Abuf[2][2][32 * 32];   // [pingpong][k-half][32q x 32k]
    __shared__ unsigned Pbuf[2][2][32 * 32];
    __shared__ unsigned mnb[32], mxb[32];

    const int tid  = threadIdx.x;
    const int wave = tid >> 6, lane = tid & 63;
    const int l15  = lane & 15, quad = lane >> 4;
    const int qt_w = wave & 1, kt_w = wave >> 1;

    // XCD-contiguous swizzle: XCD x gets swz range [x*256, x*256+256) ->
    // 8 whole (b,h) groups per XCD (2048 blocks, 8 XCDs, qt fastest).
    const int swz = (blockIdx.x & 7) * 256 + (blockIdx.x >> 3);
    const int qt = swz & 31, hb = swz >> 5;
    const int h = hb & 15, b = hb >> 4;
    const size_t qrow0 = (size_t)b * SS + (size_t)qt * 32;

    if (tid < 32) { mnb[tid] = 0x7f800000u; mxb[tid] = 0u; }

    // Q fragments (fragment-major pack: coalesced), pre-negated imag copies
    const ushort* qfb = qpk + ((size_t)(b * HH + h) * 32 + qt) * 4096 + lane * 8;
    shortx8 Aq0 = *(const shortx8*)(qfb + (qt_w * 4 + 0) * 512);
    shortx8 Aq1 = *(const shortx8*)(qfb + (qt_w * 4 + 1) * 512);
    shortx8 Aq2 = *(const shortx8*)(qfb + (qt_w * 4 + 2) * 512);
    shortx8 Aq3 = *(const shortx8*)(qfb + (qt_w * 4 + 3) * 512);
    shortx8 Nq2 = negf(Aq2), Nq3 = negf(Aq3);

    const ushort* kfb = kpk + (size_t)(b * HH + h) * 131072 + lane * 8;
    const ushort* vfb = vn  + (size_t)(b * HH + h) * 131072 + lane * 8;

    floatx4 acc[2][4];   // [q-half][Ar,Ai,Pr,Pi]
    #pragma unroll
    for (int q2 = 0; q2 < 2; ++q2)
        #pragma unroll
        for (int j = 0; j < 4; ++j)
            acc[q2][j] = (floatx4){0.f, 0.f, 0.f, 0.f};
    float rmn[4] = {1e30f, 1e30f, 1e30f, 1e30f};
    float rmx[4] = {0.f, 0.f, 0.f, 0.f};

    shortx8 KA[2][4], KB[2][4], V_[4];
    loadK(KA, kfb, 0, kt_w);

    for (int it = 0; it < 16; it += 2) {
        ATTN_ITER(it,     it + 1,        KA, KB);
        ATTN_ITER(it + 1, (it + 2) & 15, KB, KA);
    }

    // ---- per-row min/max: 16-lane shuffle, then cross-wave LDS atomics ----
    #pragma unroll
    for (int r = 0; r < 4; ++r) {
        float mn = rmn[r], mx = rmx[r];
        #pragma unroll
        for (int o = 1; o < 16; o <<= 1) {
            mn = fminf(mn, __shfl_xor(mn, o));
            mx = fmaxf(mx, __shfl_xor(mx, o));
        }
        if (l15 == 0) {
            const int q = qt_w * 16 + quad * 4 + r;
            atomicMin(&mnb[q], __float_as_uint(mn));   // mag >= 0: bits monotone
            atomicMax(&mxb[q], __float_as_uint(mx));
        }
    }
    __syncthreads();

    // ---- epilogue: o = (A - mn*P)/(mx - mn) -> bf16 pack ----
    #pragma unroll
    for (int q2 = 0; q2 < 2; ++q2) {
        #pragma unroll
        for (int r = 0; r < 4; ++r) {
            const int q = q2 * 16 + quad * 4 + r;
            const float mn = __uint_as_float(mnb[q]);
            const float mx = __uint_as_float(mxb[q]);
            const float d = mx - mn;
            const float invd = d > 0.f ? 1.f / d : 0.f;
            const float vr_ = (acc[q2][0][r] - mn * acc[q2][2][r]) * invd;
            const float vi_ = (acc[q2][1][r] - mn * acc[q2][3][r]) * invd;
            const size_t row = (qrow0 + q) * KK + h * 64 + wave * 16 + l15;
            xo[row]        = f2b(vr_);
            xo[row + 1024] = f2b(vi_);
        }
    }
}

// ---------------------------------------------------------------------------
// Complex covariance-whitening layernorm, one wave per (b,s) row.
// ---------------------------------------------------------------------------
__global__ __launch_bounds__(256) void ln_kernel(
    const float* __restrict__ xr, const float* __restrict__ xi,
    const float* __restrict__ g_rr, const float* __restrict__ g_ri,
    const float* __restrict__ g_ii,
    const float* __restrict__ b_r, const float* __restrict__ b_i,
    float* __restrict__ out)
{
    const int lane = threadIdx.x & 63;
    const int wave = threadIdx.x >> 6;
    const int row  = blockIdx.x * 4 + wave;
    const float* pr = xr + (size_t)row * DD;
    const float* pi = xi + (size_t)row * DD;

    float r[16], im[16];
    float sr = 0.f, si = 0.f;
    #pragma unroll
    for (int j = 0; j < 16; ++j) {
        r[j]  = pr[lane + 64*j];
        im[j] = pi[lane + 64*j];
        sr += r[j]; si += im[j];
    }
    #pragma unroll
    for (int o = 32; o; o >>= 1) { sr += __shfl_xor(sr, o); si += __shfl_xor(si, o); }
    const float mr = sr * (1.f / DD), mi = si * (1.f / DD);

    float srr = 0.f, sii = 0.f, sri = 0.f;
    #pragma unroll
    for (int j = 0; j < 16; ++j) {
        const float a = r[j] - mr, c = im[j] - mi;
        srr = fmaf(a, a, srr); sii = fmaf(c, c, sii); sri = fmaf(a, c, sri);
    }
    #pragma unroll
    for (int o = 32; o; o >>= 1) {
        srr += __shfl_xor(srr, o); sii += __shfl_xor(sii, o); sri += __shfl_xor(sri, o);
    }
    const float Vrr = srr * (1.f / DD) + EPS_LN;
    const float Vii = sii * (1.f / DD) + EPS_LN;
    const float Vri = sri * (1.f / DD);
    const float s  = sqrtf(Vrr * Vii - Vri * Vri);
    const float t  = sqrtf(Vrr + Vii + 2.f * s);
    const float inv = 1.f / (s * t);
    const float Wrr = (Vii + s) * inv;
    const float Wii = (Vrr + s) * inv;
    const float Wri = -Vri * inv;

    #pragma unroll
    for (int j = 0; j < 16; ++j) {
        const int d = lane + 64*j;
        const float a = r[j] - mr, c = im[j] - mi;
        const float or_ = Wrr * a + Wri * c;
        const float oi_ = Wri * a + Wii * c;
        out[(size_t)row * DD + d] = g_rr[d]*or_ + g_ri[d]*oi_ + b_r[d];
        out[(size_t)(M_ROWS) * DD + (size_t)row * DD + d] = g_ri[d]*or_ + g_ii[d]*oi_ + b_i[d];
    }
}

// ---------------------------------------------------------------------------
extern "C" void kernel_launch(void* const* d_in, const int* in_sizes, int n_in,
                              void* d_out, int out_size, void* d_ws, size_t ws_size,
                              hipStream_t stream) {
    const float* q_r  = (const float*)d_in[0];
    const float* q_i  = (const float*)d_in[1];
    const float* k_r  = (const float*)d_in[2];
    const float* k_i  = (const float*)d_in[3];
    const float* v_r  = (const float*)d_in[4];
    const float* v_i  = (const float*)d_in[5];
    const float* wq_r = (const float*)d_in[6];
    const float* wq_i = (const float*)d_in[7];
    const float* wk_r = (const float*)d_in[8];
    const float* wk_i = (const float*)d_in[9];
    const float* wv_r = (const float*)d_in[10];
    const float* wv_i = (const float*)d_in[11];
    const float* fc_r = (const float*)d_in[12];
    const float* fc_i = (const float*)d_in[13];
    const float* g_rr = (const float*)d_in[14];
    const float* g_ri = (const float*)d_in[15];
    const float* g_ii = (const float*)d_in[16];
    const float* b_r  = (const float*)d_in[17];
    const float* b_i  = (const float*)d_in[18];
    float* out = (float*)d_out;

    // Workspace: 7 units of 16 MiB = 112 MiB.
    float* ws = (float*)d_ws;
    const size_t NE = (size_t)M_ROWS * 1024;        // 4M floats = 16 MiB
    ushort* Xq   = (ushort*)(ws + 0 * NE);          // u0; later Vneg
    ushort* Xk   = (ushort*)(ws + 1 * NE);          // u1
    ushort* Xv   = (ushort*)(ws + 2 * NE);          // u2; later xo
    ushort* qpk  = (ushort*)(ws + 3 * NE);          // u3; later fr
    ushort* kpk  = (ushort*)(ws + 4 * NE);          // u4; later fi
    ushort* Bq   = (ushort*)(ws + 5 * NE);          // u5 lo
    ushort* Bk   = Bq + (size_t)KK * KK;            // u5 hi
    ushort* Bv   = (ushort*)(ws + 6 * NE);          // u6 lo
    ushort* Bf   = Bv + (size_t)KK * KK;            // u6 hi
    ushort* Vneg = (ushort*)(ws + 0 * NE);          // aliases dead Xq
    ushort* xo   = (ushort*)(ws + 2 * NE);          // aliases dead Xv
    float*  fr   = ws + 3 * NE;                     // aliases dead qpk
    float*  fi   = ws + 4 * NE;                     // aliases dead kpk

    // bf16 operand packing
    pack_x<<<dim3(4096, 3), 256, 0, stream>>>(q_r, q_i, k_r, k_i, v_r, v_i, Xq, Xk, Xv);
    pack_w<<<dim3(1024, 4), 256, 0, stream>>>(wq_r, wq_i, wk_r, wk_i, wv_r, wv_i,
                                              fc_r, fc_i, Bq, Bk, Bv, Bf);

    // Q/K projections (q gets 1/sqrt(DK) folded in)
    bgemm_qk<<<dim3(KK / BN, M_ROWS / BM, 2), 256, 0, stream>>>(
        Xq, Xk, Bq, Bk, qpk, kpk);

    // V projection (separate dispatch: writes alias dead Xq)
    bgemm_v<<<dim3(KK / BN, M_ROWS / BM), 256, 0, stream>>>(Xv, Bv, Vneg);

    // cooperative MFMA attention + MagMinMaxNorm -> bf16 [4096][2048] pack
    attn_mfma<<<dim3(2048), 256, 0, stream>>>(qpk, kpk, Vneg, xo);

    // output projection + residual (bf16 MFMA, fp32 out)
    bgemm_fc<<<dim3(KK / BN, M_ROWS / BM), 256, 0, stream>>>(xo, Bf, fr, fi, q_r, q_i);

    // complex layernorm -> d_out [2,B,S,D]
    ln_kernel<<<M_ROWS / 4, 256, 0, stream>>>(fr, fi, g_rr, g_ri, g_ii, b_r, b_i, out);
}

// Round 3
// 509.027 us; speedup vs baseline: 1.2821x; 1.0347x over previous
//
#include <hip/hip_runtime.h>
#include <hip/hip_bf16.h>

// Problem constants
#define BB 4
#define SS 1024
#define DD 1024
#define HH 16
#define DKH 64
#define EPS_LN 1e-6f

#define M_ROWS 4096   // B*S
#define KK 2048       // concatenated complex K (re|im)

typedef float  floatx4 __attribute__((ext_vector_type(4)));
typedef short  shortx8 __attribute__((ext_vector_type(8)));
#define MFMA16(a, b, c) __builtin_amdgcn_mfma_f32_16x16x32_bf16(a, b, c, 0, 0, 0)

// pack two floats into one u32 of 2 bf16 (low = first) via single HW op (RNE)
__device__ __forceinline__ unsigned pk2(float lo, float hi) {
    unsigned u;
    asm("v_cvt_pk_bf16_f32 %0, %1, %2" : "=v"(u) : "v"(lo), "v"(hi));
    return u;
}

// float -> bf16 (RNE) via the same HW op
__device__ __forceinline__ ushort f2b(float x) {
    return (ushort)(pk2(x, x) & 0xffffu);
}

// negate a bf16x8 fragment (flip sign bits)
__device__ __forceinline__ shortx8 negf(shortx8 x) {
    shortx8 r;
    #pragma unroll
    for (int i = 0; i < 8; ++i) r[i] = (short)(x[i] ^ (short)0x8000);
    return r;
}

// per-32-bit-word [lo=vr, hi=-vi] -> [lo=vi, hi=vr]  (rotate16 + flip lo sign)
__device__ __forceinline__ shortx8 vswap(shortx8 v) {
    union { shortx8 s; unsigned u[4]; } a, b;
    a.s = v;
    #pragma unroll
    for (int i = 0; i < 4; ++i) {
        const unsigned w = a.u[i];
        b.u[i] = ((w >> 16) | (w << 16)) ^ 0x00008000u;
    }
    return b.s;
}

// async global->LDS, 16 bytes per lane (lane-contiguous LDS layout required)
__device__ __forceinline__ void gl16(const void* g, void* l) {
    __builtin_amdgcn_global_load_lds(
        (const __attribute__((address_space(1))) unsigned int*)g,
        (__attribute__((address_space(3))) unsigned int*)l, 16, 0, 0);
}

// ---------------------------------------------------------------------------
// pack_x: [4096][1024] fp32 pair -> [4096][2048] bf16  (row = [re | im])
// ---------------------------------------------------------------------------
__global__ __launch_bounds__(256) void pack_x(
    const float* __restrict__ qr, const float* __restrict__ qi,
    const float* __restrict__ kr, const float* __restrict__ ki,
    const float* __restrict__ vr, const float* __restrict__ vi,
    ushort* __restrict__ Xq, ushort* __restrict__ Xk, ushort* __restrict__ Xv)
{
    const int t = blockIdx.y;
    const float* pr = t == 0 ? qr : t == 1 ? kr : vr;
    const float* pi = t == 0 ? qi : t == 1 ? ki : vi;
    ushort* X = t == 0 ? Xq : t == 1 ? Xk : Xv;
    const int idx = blockIdx.x * 256 + threadIdx.x;
    const int row = idx >> 8, c4 = (idx & 255) * 4;
    float4 a = *(const float4*)(pr + (size_t)row * 1024 + c4);
    float4 b = *(const float4*)(pi + (size_t)row * 1024 + c4);
    ushort4 ua; ua.x = f2b(a.x); ua.y = f2b(a.y); ua.z = f2b(a.z); ua.w = f2b(a.w);
    ushort4 ub; ub.x = f2b(b.x); ub.y = f2b(b.y); ub.z = f2b(b.z); ub.w = f2b(b.w);
    *(ushort4*)(X + (size_t)row * KK + c4)        = ua;
    *(ushort4*)(X + (size_t)row * KK + 1024 + c4) = ub;
}

// ---------------------------------------------------------------------------
// pack_w: [1024][1024] fp32 pair -> [2048][2048] bf16
//   row n       = [ wr[n] | -wi[n] ]   (produces Yr)
//   row 1024+n  = [ wi[n] |  wr[n] ]   (produces Yi)
// ---------------------------------------------------------------------------
__global__ __launch_bounds__(256) void pack_w(
    const float* __restrict__ ar, const float* __restrict__ ai,
    const float* __restrict__ br, const float* __restrict__ bi,
    const float* __restrict__ cr, const float* __restrict__ ci,
    const float* __restrict__ dr, const float* __restrict__ di,
    ushort* __restrict__ Bq, ushort* __restrict__ Bk,
    ushort* __restrict__ Bv, ushort* __restrict__ Bf)
{
    const int t = blockIdx.y;
    const float* wr = t == 0 ? ar : t == 1 ? br : t == 2 ? cr : dr;
    const float* wi = t == 0 ? ai : t == 1 ? bi : t == 2 ? ci : di;
    ushort* Bo = t == 0 ? Bq : t == 1 ? Bk : t == 2 ? Bv : Bf;
    const int idx = blockIdx.x * 256 + threadIdx.x;
    const int n = idx >> 8, c4 = (idx & 255) * 4;
    float4 a = *(const float4*)(wr + (size_t)n * 1024 + c4);
    float4 b = *(const float4*)(wi + (size_t)n * 1024 + c4);
    ushort4 ua; ua.x = f2b(a.x);  ua.y = f2b(a.y);  ua.z = f2b(a.z);  ua.w = f2b(a.w);
    ushort4 ub; ub.x = f2b(b.x);  ub.y = f2b(b.y);  ub.z = f2b(b.z);  ub.w = f2b(b.w);
    ushort4 un; un.x = f2b(-b.x); un.y = f2b(-b.y); un.z = f2b(-b.z); un.w = f2b(-b.w);
    *(ushort4*)(Bo + (size_t)n * KK + c4)                 = ua;
    *(ushort4*)(Bo + (size_t)n * KK + 1024 + c4)          = un;
    *(ushort4*)(Bo + (size_t)(1024 + n) * KK + c4)        = ub;
    *(ushort4*)(Bo + (size_t)(1024 + n) * KK + 1024 + c4) = ua;
}

// ---------------------------------------------------------------------------
// bf16 MFMA GEMM, 128x256 tile, BK=64, 8 waves (2M x 4N), 512 threads.
// C[M, N=2048] = A[M,2048] . B[N,2048]^T
//  - global_load_lds staging, double-buffered by K-step parity (96 KiB LDS)
//  - counted vmcnt(6): prefetch distance 2 K-steps, never drained in-loop
//  - T2 swizzle: linear LDS dest + inverse-swizzled per-lane global source
//    (chunk c' stores global chunk c'^(row&7)); ds_read applies the same XOR
//    -> b128 reads hit 8 lanes/bank-quad on distinct rows = zero conflicts
//  - T5 setprio around the 32-MFMA cluster
// Epilogue modes (fragment-major packs so attn loads are lane-coalesced):
//   0: Q frag pack   3: K frag pack   1: V frag pack [vr,-vi]
//   2: fp32 out + residual
// ---------------------------------------------------------------------------
#define GBM 128
#define GBN 256
#define GBK 64

#define GSTAGE(P, KT) do {                                                    \
    const ushort* ga_ = gA + (KT) * GBK;                                      \
    const ushort* gb_ = gB + (KT) * GBK;                                      \
    ushort* la_ = &As[P][st8];                                                \
    ushort* lb_ = &Bs[P][st8];                                                \
    gl16(ga_,                la_);                                            \
    gl16(ga_ + 64 * KK,      la_ + 4096);                                     \
    gl16(gb_,                lb_);                                            \
    gl16(gb_ + 64 * KK,      lb_ + 4096);                                     \
    gl16(gb_ + 128 * KK,     lb_ + 8192);                                     \
    gl16(gb_ + 192 * KK,     lb_ + 12288);                                    \
} while (0)

#define GKSTEP(P, VM, DOSTAGE) do {                                           \
    asm volatile("s_waitcnt vmcnt(" #VM ")" ::: "memory");                    \
    __builtin_amdgcn_s_barrier();                                             \
    __builtin_amdgcn_sched_barrier(0);                                        \
    const ushort* Ap = As[P];                                                 \
    const ushort* Bp = Bs[P];                                                 \
    shortx8 a[4][2], b[4][2];                                                 \
    _Pragma("unroll")                                                         \
    for (int f = 0; f < 4; ++f) {                                             \
        const int ra = (wm + f * 16 + l15) * GBK;                             \
        const int rb = (wn + f * 16 + l15) * GBK;                             \
        a[f][0] = *(const shortx8*)&Ap[ra + ca0];                             \
        a[f][1] = *(const shortx8*)&Ap[ra + ca1];                             \
        b[f][0] = *(const shortx8*)&Bp[rb + ca0];                             \
        b[f][1] = *(const shortx8*)&Bp[rb + ca1];                             \
    }                                                                         \
    __builtin_amdgcn_s_setprio(1);                                            \
    _Pragma("unroll")                                                         \
    for (int fm = 0; fm < 4; ++fm)                                            \
        _Pragma("unroll")                                                     \
        for (int fn = 0; fn < 4; ++fn) {                                      \
            acc[fm][fn] = MFMA16(a[fm][0], b[fn][0], acc[fm][fn]);            \
            acc[fm][fn] = MFMA16(a[fm][1], b[fn][1], acc[fm][fn]);            \
        }                                                                     \
    __builtin_amdgcn_s_setprio(0);                                            \
    asm volatile("s_waitcnt lgkmcnt(0)" ::: "memory");                        \
    __builtin_amdgcn_sched_barrier(0);                                        \
    __builtin_amdgcn_s_barrier();                                             \
    if (DOSTAGE) GSTAGE(P, kt + 2);                                           \
    ++kt;                                                                     \
} while (0)

__device__ __forceinline__ void bgemm_body(
    const ushort* __restrict__ A, const ushort* __restrict__ Bm,
    void* __restrict__ out0, void* __restrict__ out1,
    const float* __restrict__ resr, const float* __restrict__ resi,
    float scale, int mode, int bx, int by)
{
    __shared__ __align__(16) ushort As[2][GBM * GBK];   // 2 x 16 KiB
    __shared__ __align__(16) ushort Bs[2][GBN * GBK];   // 2 x 32 KiB

    const int t = threadIdx.x;
    const int lane = t & 63, wave = t >> 6;
    const int l15 = lane & 15, quad = lane >> 4;
    const int wm = (wave >> 2) * 64;        // wave M offset (2 M-waves)
    const int wn = (wave & 3) * 64;         // wave N offset (4 N-waves)
    const int m0 = by * GBM, n0 = bx * GBN;

    // staging: thread t covers 16B chunk q=t (+512 strides); row = q>>3,
    // LDS chunk c' = q&7 holds global chunk c = c' ^ (row&7)
    const int srow = t >> 3;
    const int schk = (t & 7) ^ (srow & 7);
    const int st8  = t * 8;
    const ushort* gA = A  + (size_t)(m0 + srow) * KK + schk * 8;
    const ushort* gB = Bm + (size_t)(n0 + srow) * KK + schk * 8;

    // ds_read chunk offsets (in ushorts): logical chunk (ks*4+quad) ^ (row&7)
    const int rm  = l15 & 7;
    const int ca0 = ((quad)     ^ rm) * 8;
    const int ca1 = ((4 + quad) ^ rm) * 8;

    floatx4 acc[4][4];
    #pragma unroll
    for (int fm = 0; fm < 4; ++fm)
        #pragma unroll
        for (int fn = 0; fn < 4; ++fn)
            acc[fm][fn] = (floatx4){0.f, 0.f, 0.f, 0.f};

    GSTAGE(0, 0);
    GSTAGE(1, 1);

    int kt = 0;
    for (int i = 0; i < 15; ++i) {
        GKSTEP(0, 6, 1);
        GKSTEP(1, 6, 1);
    }
    GKSTEP(0, 6, 0);   // kt = 30, STAGE(31) still in flight
    GKSTEP(1, 0, 0);   // kt = 31, drain

    // Epilogue. C layout: col = lane&15, row = quad*4 + reg.
    #pragma unroll
    for (int fm = 0; fm < 4; ++fm) {
        #pragma unroll
        for (int fn = 0; fn < 4; ++fn) {
            #pragma unroll
            for (int r = 0; r < 4; ++r) {
                const int m = m0 + wm + fm * 16 + quad * 4 + r;
                const int n = n0 + wn + fn * 16 + l15;
                const float v = acc[fm][fn][r] * scale;
                const int nn = n & 1023;
                const int hh = nn >> 6;
                const int bb = m >> 10, s = m & 1023;
                if (mode == 0) {           // Q fragment pack (32-row tiles)
                    const int dk = (n < 1024 ? 0 : 64) + (nn & 63);
                    const int tq = s >> 5, row = s & 31;
                    ushort* Qb = (ushort*)out0 +
                        ((size_t)(bb * HH + hh) * 32 + tq) * 4096;
                    const int off = ((row >> 4) * 4 + (dk >> 5)) * 512 +
                                    ((dk >> 3) & 3) * 128 + (row & 15) * 8 + (dk & 7);
                    Qb[off] = f2b(v);
                } else if (mode == 3) {    // K fragment pack (64-row tiles)
                    const int dk = (n < 1024 ? 0 : 64) + (nn & 63);
                    const int tt = s >> 6, row = s & 63;
                    ushort* Kb = (ushort*)out0 +
                        ((size_t)(bb * HH + hh) * 16 + tt) * 8192;
                    const int off = ((row >> 4) * 4 + (dk >> 5)) * 512 +
                                    ((dk >> 3) & 3) * 128 + (row & 15) * 8 + (dk & 7);
                    Kb[off] = f2b(v);
                } else if (mode == 1) {    // V fragment pack, interleaved [vr,-vi]
                    const int dv = nn & 63;
                    const int c = 2 * s + (n < 1024 ? 0 : 1);
                    ushort* Vb = (ushort*)out0 + (size_t)(bb * HH + hh) * 131072;
                    const int off = (((c >> 7) * 4 + (dv >> 4)) * 4 + ((c >> 5) & 3)) * 512 +
                                    ((c >> 3) & 3) * 128 + (dv & 15) * 8 + (c & 7);
                    Vb[off] = f2b(n < 1024 ? v : -v);
                } else {                   // fc: fp32 out + residual
                    const size_t off = (size_t)m * 1024 + nn;
                    if (n < 1024) ((float*)out0)[off] = v + resr[off];
                    else          ((float*)out1)[off] = v + resi[off];
                }
            }
        }
    }
}

// Q/K projection GEMMs: blockIdx.z selects {Q, K}
__global__ __launch_bounds__(512) void bgemm_qk(
    const ushort* __restrict__ Xq, const ushort* __restrict__ Xk,
    const ushort* __restrict__ Bq, const ushort* __restrict__ Bk,
    ushort* __restrict__ qpk, ushort* __restrict__ kpk)
{
    const int z = blockIdx.z;
    bgemm_body(z == 0 ? Xq : Xk, z == 0 ? Bq : Bk,
               z == 0 ? (void*)qpk : (void*)kpk, nullptr, nullptr, nullptr,
               z == 0 ? 0.125f : 1.0f, z == 0 ? 0 : 3, blockIdx.x, blockIdx.y);
}

// V projection GEMM (separate dispatch: its output aliases dead Xq)
__global__ __launch_bounds__(512) void bgemm_v(
    const ushort* __restrict__ Xv, const ushort* __restrict__ Bv,
    ushort* __restrict__ Vneg)
{
    bgemm_body(Xv, Bv, (void*)Vneg, nullptr, nullptr, nullptr,
               1.0f, 1, blockIdx.x, blockIdx.y);
}

// fc GEMM: fp32 out + residual
__global__ __launch_bounds__(512) void bgemm_fc(
    const ushort* __restrict__ A, const ushort* __restrict__ Bm,
    float* __restrict__ fr, float* __restrict__ fi,
    const float* __restrict__ resr, const float* __restrict__ resi)
{
    bgemm_body(A, Bm, fr, fi, resr, resi, 1.0f, 2, blockIdx.x, blockIdx.y);
}

// ---------------------------------------------------------------------------
// Cooperative MFMA attention + exact streamed MagMinMaxNorm, TK=64/iteration.
//   o = (A - mn*P)/(mx - mn);  A = sum attn*v,  P = sum (attn/|attn|)*v
// All Q/K/V global loads are lane-coalesced (fragment-major packs).
// K register double-buffered; V loaded at iteration top; Vswap derived
// in-register. Per-iteration barrier is lgkmcnt(0)-only. LDS A/P ping-pong,
// XOR-swizzled. 1-D grid, XCD-contiguous swizzle.
// Output: bf16 pack xo[m][2048] = [o_r (h*64+dv) | o_i].
// ---------------------------------------------------------------------------
#define SWZ(row, col) (((row) << 5) + ((col) ^ (((row) & 7) << 2)))

__device__ __forceinline__ void loadK(shortx8 (&K)[2][4], const ushort* kfb,
                                      int t, int kt_w) {
    #pragma unroll
    for (int kt2 = 0; kt2 < 2; ++kt2)
        #pragma unroll
        for (int f = 0; f < 4; ++f)
            K[kt2][f] = *(const shortx8*)(kfb + t * 8192 +
                                          ((kt_w * 2 + kt2) * 4 + f) * 512);
}

__device__ __forceinline__ void loadVn(shortx8 (&V)[4], const ushort* vfb,
                                       int t, int wave) {
    #pragma unroll
    for (int f = 0; f < 4; ++f)
        V[f] = *(const shortx8*)(vfb + ((t * 4 + wave) * 4 + f) * 512);
}

#define ATTN_ITER(IT, NX, KC, KN)                                             \
  {                                                                           \
    loadVn(V_, vfb, (IT), wave);                                              \
    const int p_ = (IT) & 1;                                                  \
    unsigned* Ab = Abuf[p_][kt_w];                                            \
    unsigned* Pb = Pbuf[p_][kt_w];                                            \
    floatx4 cr[2], ci[2];                                                     \
    _Pragma("unroll")                                                         \
    for (int kt2 = 0; kt2 < 2; ++kt2) {                                       \
      floatx4 r_ = (floatx4){0.f, 0.f, 0.f, 0.f};                             \
      floatx4 i_ = (floatx4){0.f, 0.f, 0.f, 0.f};                             \
      r_ = MFMA16(Aq0, KC[kt2][0], r_); r_ = MFMA16(Aq1, KC[kt2][1], r_);     \
      r_ = MFMA16(Nq2, KC[kt2][2], r_); r_ = MFMA16(Nq3, KC[kt2][3], r_);     \
      i_ = MFMA16(Aq2, KC[kt2][0], i_); i_ = MFMA16(Aq3, KC[kt2][1], i_);     \
      i_ = MFMA16(Aq0, KC[kt2][2], i_); i_ = MFMA16(Aq1, KC[kt2][3], i_);     \
      cr[kt2] = r_; ci[kt2] = i_;                                             \
    }                                                                         \
    loadK(KN, kfb, (NX), kt_w);                                               \
    _Pragma("unroll")                                                         \
    for (int kt2 = 0; kt2 < 2; ++kt2) {                                       \
      _Pragma("unroll")                                                       \
      for (int r = 0; r < 4; ++r) {                                           \
        const float ar = cr[kt2][r], ai = ci[kt2][r];                         \
        const float s2 = fmaf(ar, ar, ai * ai);                               \
        const float irm = s2 > 0.f ? rsqrtf(s2) : 0.f;                        \
        const float mag = s2 * irm;                                           \
        rmn[r] = fminf(rmn[r], mag);                                          \
        rmx[r] = fmaxf(rmx[r], mag);                                          \
        const int row_ = qt_w * 16 + quad * 4 + r;                            \
        const int w_ = SWZ(row_, kt2 * 16 + l15);                             \
        Ab[w_] = pk2(ar, ai);                                                 \
        Pb[w_] = pk2(ar * irm, ai * irm);                                     \
      }                                                                       \
    }                                                                         \
    asm volatile("s_waitcnt lgkmcnt(0)" ::: "memory");                        \
    __builtin_amdgcn_s_barrier();                                             \
    const shortx8 Vs0 = vswap(V_[0]), Vs1 = vswap(V_[1]);                     \
    const shortx8 Vs2 = vswap(V_[2]), Vs3 = vswap(V_[3]);                     \
    const unsigned* A0 = Abuf[p_][0];                                         \
    const unsigned* A1 = Abuf[p_][1];                                         \
    const unsigned* P0 = Pbuf[p_][0];                                         \
    const unsigned* P1 = Pbuf[p_][1];                                         \
    __builtin_amdgcn_s_setprio(1);                                            \
    _Pragma("unroll")                                                         \
    for (int q2 = 0; q2 < 2; ++q2) {                                          \
      const int row_ = q2 * 16 + l15;                                         \
      const int rb_ = row_ * 32, rm_ = (row_ & 7) << 2;                       \
      const int c0_ = rb_ + ((quad * 4) ^ rm_);                               \
      const int c1_ = rb_ + ((16 + quad * 4) ^ rm_);                          \
      shortx8 Af0 = *(const shortx8*)&A0[c0_];                                \
      shortx8 Af1 = *(const shortx8*)&A0[c1_];                                \
      shortx8 Af2 = *(const shortx8*)&A1[c0_];                                \
      shortx8 Af3 = *(const shortx8*)&A1[c1_];                                \
      shortx8 Pf0 = *(const shortx8*)&P0[c0_];                                \
      shortx8 Pf1 = *(const shortx8*)&P0[c1_];                                \
      shortx8 Pf2 = *(const shortx8*)&P1[c0_];                                \
      shortx8 Pf3 = *(const shortx8*)&P1[c1_];                                \
      acc[q2][0] = MFMA16(Af0, V_[0], acc[q2][0]);                            \
      acc[q2][0] = MFMA16(Af1, V_[1], acc[q2][0]);                            \
      acc[q2][0] = MFMA16(Af2, V_[2], acc[q2][0]);                            \
      acc[q2][0] = MFMA16(Af3, V_[3], acc[q2][0]);                            \
      acc[q2][1] = MFMA16(Af0, Vs0, acc[q2][1]);                              \
      acc[q2][1] = MFMA16(Af1, Vs1, acc[q2][1]);                              \
      acc[q2][1] = MFMA16(Af2, Vs2, acc[q2][1]);                              \
      acc[q2][1] = MFMA16(Af3, Vs3, acc[q2][1]);                              \
      acc[q2][2] = MFMA16(Pf0, V_[0], acc[q2][2]);                            \
      acc[q2][2] = MFMA16(Pf1, V_[1], acc[q2][2]);                            \
      acc[q2][2] = MFMA16(Pf2, V_[2], acc[q2][2]);                            \
      acc[q2][2] = MFMA16(Pf3, V_[3], acc[q2][2]);                            \
      acc[q2][3] = MFMA16(Pf0, Vs0, acc[q2][3]);                              \
      acc[q2][3] = MFMA16(Pf1, Vs1, acc[q2][3]);                              \
      acc[q2][3] = MFMA16(Pf2, Vs2, acc[q2][3]);                              \
      acc[q2][3] = MFMA16(Pf3, Vs3, acc[q2][3]);                              \
    }                                                                         \
    __builtin_amdgcn_s_setprio(0);                                            \
  }

__global__ __launch_bounds__(256) void attn_mfma(
    const ushort* __restrict__ qpk, const ushort* __restrict__ kpk,
    const ushort* __restrict__ vn, ushort* __restrict__ xo)
{
    __shared__ unsigned Abuf[2][2][32 * 32];   // [pingpong][k-half][32q x 32k]
    __shared__ unsigned Pbuf[2][2][32 * 32];
    __shared__ unsigned mnb[32], mxb[32];

    const int tid  = threadIdx.x;
    const int wave = tid >> 6, lane = tid & 63;
    const int l15  = lane & 15, quad = lane >> 4;
    const int qt_w = wave & 1, kt_w = wave >> 1;

    // XCD-contiguous swizzle: XCD x gets swz range [x*256, x*256+256) ->
    // 8 whole (b,h) groups per XCD (2048 blocks, 8 XCDs, qt fastest).
    const int swz = (blockIdx.x & 7) * 256 + (blockIdx.x >> 3);
    const int qt = swz & 31, hb = swz >> 5;
    const int h = hb & 15, b = hb >> 4;
    const size_t qrow0 = (size_t)b * SS + (size_t)qt * 32;

    if (tid < 32) { mnb[tid] = 0x7f800000u; mxb[tid] = 0u; }

    // Q fragments (fragment-major pack: coalesced), pre-negated imag copies
    const ushort* qfb = qpk + ((size_t)(b * HH + h) * 32 + qt) * 4096 + lane * 8;
    shortx8 Aq0 = *(const shortx8*)(qfb + (qt_w * 4 + 0) * 512);
    shortx8 Aq1 = *(const shortx8*)(qfb + (qt_w * 4 + 1) * 512);
    shortx8 Aq2 = *(const shortx8*)(qfb + (qt_w * 4 + 2) * 512);
    shortx8 Aq3 = *(const shortx8*)(qfb + (qt_w * 4 + 3) * 512);
    shortx8 Nq2 = negf(Aq2), Nq3 = negf(Aq3);

    const ushort* kfb = kpk + (size_t)(b * HH + h) * 131072 + lane * 8;
    const ushort* vfb = vn  + (size_t)(b * HH + h) * 131072 + lane * 8;

    floatx4 acc[2][4];   // [q-half][Ar,Ai,Pr,Pi]
    #pragma unroll
    for (int q2 = 0; q2 < 2; ++q2)
        #pragma unroll
        for (int j = 0; j < 4; ++j)
            acc[q2][j] = (floatx4){0.f, 0.f, 0.f, 0.f};
    float rmn[4] = {1e30f, 1e30f, 1e30f, 1e30f};
    float rmx[4] = {0.f, 0.f, 0.f, 0.f};

    shortx8 KA[2][4], KB[2][4], V_[4];
    loadK(KA, kfb, 0, kt_w);

    for (int it = 0; it < 16; it += 2) {
        ATTN_ITER(it,     it + 1,        KA, KB);
        ATTN_ITER(it + 1, (it + 2) & 15, KB, KA);
    }

    // ---- per-row min/max: 16-lane shuffle, then cross-wave LDS atomics ----
    #pragma unroll
    for (int r = 0; r < 4; ++r) {
        float mn = rmn[r], mx = rmx[r];
        #pragma unroll
        for (int o = 1; o < 16; o <<= 1) {
            mn = fminf(mn, __shfl_xor(mn, o));
            mx = fmaxf(mx, __shfl_xor(mx, o));
        }
        if (l15 == 0) {
            const int q = qt_w * 16 + quad * 4 + r;
            atomicMin(&mnb[q], __float_as_uint(mn));   // mag >= 0: bits monotone
            atomicMax(&mxb[q], __float_as_uint(mx));
        }
    }
    __syncthreads();

    // ---- epilogue: o = (A - mn*P)/(mx - mn) -> bf16 pack ----
    #pragma unroll
    for (int q2 = 0; q2 < 2; ++q2) {
        #pragma unroll
        for (int r = 0; r < 4; ++r) {
            const int q = q2 * 16 + quad * 4 + r;
            const float mn = __uint_as_float(mnb[q]);
            const float mx = __uint_as_float(mxb[q]);
            const float d = mx - mn;
            const float invd = d > 0.f ? 1.f / d : 0.f;
            const float vr_ = (acc[q2][0][r] - mn * acc[q2][2][r]) * invd;
            const float vi_ = (acc[q2][1][r] - mn * acc[q2][3][r]) * invd;
            const size_t row = (qrow0 + q) * KK + h * 64 + wave * 16 + l15;
            xo[row]        = f2b(vr_);
            xo[row + 1024] = f2b(vi_);
        }
    }
}

// ---------------------------------------------------------------------------
// Complex covariance-whitening layernorm, one wave per (b,s) row.
// ---------------------------------------------------------------------------
__global__ __launch_bounds__(256) void ln_kernel(
    const float* __restrict__ xr, const float* __restrict__ xi,
    const float* __restrict__ g_rr, const float* __restrict__ g_ri,
    const float* __restrict__ g_ii,
    const float* __restrict__ b_r, const float* __restrict__ b_i,
    float* __restrict__ out)
{
    const int lane = threadIdx.x & 63;
    const int wave = threadIdx.x >> 6;
    const int row  = blockIdx.x * 4 + wave;
    const float* pr = xr + (size_t)row * DD;
    const float* pi = xi + (size_t)row * DD;

    float r[16], im[16];
    float sr = 0.f, si = 0.f;
    #pragma unroll
    for (int j = 0; j < 16; ++j) {
        r[j]  = pr[lane + 64*j];
        im[j] = pi[lane + 64*j];
        sr += r[j]; si += im[j];
    }
    #pragma unroll
    for (int o = 32; o; o >>= 1) { sr += __shfl_xor(sr, o); si += __shfl_xor(si, o); }
    const float mr = sr * (1.f / DD), mi = si * (1.f / DD);

    float srr = 0.f, sii = 0.f, sri = 0.f;
    #pragma unroll
    for (int j = 0; j < 16; ++j) {
        const float a = r[j] - mr, c = im[j] - mi;
        srr = fmaf(a, a, srr); sii = fmaf(c, c, sii); sri = fmaf(a, c, sri);
    }
    #pragma unroll
    for (int o = 32; o; o >>= 1) {
        srr += __shfl_xor(srr, o); sii += __shfl_xor(sii, o); sri += __shfl_xor(sri, o);
    }
    const float Vrr = srr * (1.f / DD) + EPS_LN;
    const float Vii = sii * (1.f / DD) + EPS_LN;
    const float Vri = sri * (1.f / DD);
    const float s  = sqrtf(Vrr * Vii - Vri * Vri);
    const float t  = sqrtf(Vrr + Vii + 2.f * s);
    const float inv = 1.f / (s * t);
    const float Wrr = (Vii + s) * inv;
    const float Wii = (Vrr + s) * inv;
    const float Wri = -Vri * inv;

    #pragma unroll
    for (int j = 0; j < 16; ++j) {
        const int d = lane + 64*j;
        const float a = r[j] - mr, c = im[j] - mi;
        const float or_ = Wrr * a + Wri * c;
        const float oi_ = Wri * a + Wii * c;
        out[(size_t)row * DD + d] = g_rr[d]*or_ + g_ri[d]*oi_ + b_r[d];
        out[(size_t)(M_ROWS) * DD + (size_t)row * DD + d] = g_ri[d]*or_ + g_ii[d]*oi_ + b_i[d];
    }
}

// ---------------------------------------------------------------------------
extern "C" void kernel_launch(void* const* d_in, const int* in_sizes, int n_in,
                              void* d_out, int out_size, void* d_ws, size_t ws_size,
                              hipStream_t stream) {
    const float* q_r  = (const float*)d_in[0];
    const float* q_i  = (const float*)d_in[1];
    const float* k_r  = (const float*)d_in[2];
    const float* k_i  = (const float*)d_in[3];
    const float* v_r  = (const float*)d_in[4];
    const float* v_i  = (const float*)d_in[5];
    const float* wq_r = (const float*)d_in[6];
    const float* wq_i = (const float*)d_in[7];
    const float* wk_r = (const float*)d_in[8];
    const float* wk_i = (const float*)d_in[9];
    const float* wv_r = (const float*)d_in[10];
    const float* wv_i = (const float*)d_in[11];
    const float* fc_r = (const float*)d_in[12];
    const float* fc_i = (const float*)d_in[13];
    const float* g_rr = (const float*)d_in[14];
    const float* g_ri = (const float*)d_in[15];
    const float* g_ii = (const float*)d_in[16];
    const float* b_r  = (const float*)d_in[17];
    const float* b_i  = (const float*)d_in[18];
    float* out = (float*)d_out;

    // Workspace: 7 units of 16 MiB = 112 MiB.
    float* ws = (float*)d_ws;
    const size_t NE = (size_t)M_ROWS * 1024;        // 4M floats = 16 MiB
    ushort* Xq   = (ushort*)(ws + 0 * NE);          // u0; later Vneg
    ushort* Xk   = (ushort*)(ws + 1 * NE);          // u1
    ushort* Xv   = (ushort*)(ws + 2 * NE);          // u2; later xo
    ushort* qpk  = (ushort*)(ws + 3 * NE);          // u3; later fr
    ushort* kpk  = (ushort*)(ws + 4 * NE);          // u4; later fi
    ushort* Bq   = (ushort*)(ws + 5 * NE);          // u5 lo
    ushort* Bk   = Bq + (size_t)KK * KK;            // u5 hi
    ushort* Bv   = (ushort*)(ws + 6 * NE);          // u6 lo
    ushort* Bf   = Bv + (size_t)KK * KK;            // u6 hi
    ushort* Vneg = (ushort*)(ws + 0 * NE);          // aliases dead Xq
    ushort* xo   = (ushort*)(ws + 2 * NE);          // aliases dead Xv
    float*  fr   = ws + 3 * NE;                     // aliases dead qpk
    float*  fi   = ws + 4 * NE;                     // aliases dead kpk

    // bf16 operand packing
    pack_x<<<dim3(4096, 3), 256, 0, stream>>>(q_r, q_i, k_r, k_i, v_r, v_i, Xq, Xk, Xv);
    pack_w<<<dim3(1024, 4), 256, 0, stream>>>(wq_r, wq_i, wk_r, wk_i, wv_r, wv_i,
                                              fc_r, fc_i, Bq, Bk, Bv, Bf);

    // Q/K projections (q gets 1/sqrt(DK) folded in): 128x256 tiles, 512 thr
    bgemm_qk<<<dim3(KK / GBN, M_ROWS / GBM, 2), 512, 0, stream>>>(
        Xq, Xk, Bq, Bk, qpk, kpk);

    // V projection (separate dispatch: writes alias dead Xq)
    bgemm_v<<<dim3(KK / GBN, M_ROWS / GBM), 512, 0, stream>>>(Xv, Bv, Vneg);

    // cooperative MFMA attention + MagMinMaxNorm -> bf16 [4096][2048] pack
    attn_mfma<<<dim3(2048), 256, 0, stream>>>(qpk, kpk, Vneg, xo);

    // output projection + residual (bf16 MFMA, fp32 out)
    bgemm_fc<<<dim3(KK / GBN, M_ROWS / GBM), 512, 0, stream>>>(xo, Bf, fr, fi, q_r, q_i);

    // complex layernorm -> d_out [2,B,S,D]
    ln_kernel<<<M_ROWS / 4, 256, 0, stream>>>(fr, fi, g_rr, g_ri, g_ii, b_r, b_i, out);
}